// Round 3
// baseline (746.845 us; speedup 1.0000x reference)
//
#include <hip/hip_runtime.h>
#include <hip/hip_bf16.h>

typedef float f32x4 __attribute__((ext_vector_type(4)));
typedef short bf16x8 __attribute__((ext_vector_type(8)));
typedef unsigned short u16;

namespace {

constexpr float EPSf = 1e-5f;

__device__ __forceinline__ u16 f2b(float f) {
  __hip_bfloat16 h = __float2bfloat16(f);
  return *(u16*)&h;
}

// ---------------------------------------------------------------------------
// prep: blocks 0..63 -> per-n AT (padded, transposed, bf16) + bias2d table
//       block 64     -> wT, w2T, folded BN coefficients
// ---------------------------------------------------------------------------
__global__ __launch_bounds__(256) void prep(
    const float* __restrict__ A, const float* __restrict__ Wc, const float* __restrict__ bc,
    const float* __restrict__ g1, const float* __restrict__ b1,
    const float* __restrict__ m1, const float* __restrict__ v1,
    const float* __restrict__ tcw, const float* __restrict__ tb,
    const float* __restrict__ g2, const float* __restrict__ b2,
    const float* __restrict__ m2, const float* __restrict__ v2,
    u16* __restrict__ atk, u16* __restrict__ wt, u16* __restrict__ w2t,
    float* __restrict__ invadd, float* __restrict__ bias2d)
{
  const int b = blockIdx.x, tid = threadIdx.x;
  if (b < 64) {
    __shared__ float Al[1875];
    __shared__ float SAl[75];
    const float* An = A + b * 1875;
    for (int e = tid; e < 1875; e += 256) Al[e] = An[e];
    __syncthreads();
    if (tid < 75) {
      int k = tid / 25, w = tid % 25;
      float s = 0.f;
      for (int v = 0; v < 25; ++v) s += Al[k * 625 + v * 25 + w];
      SAl[tid] = s;
    }
    __syncthreads();
    // AT[k][w(32)][v(32)] = A[n][k][v][w], zero-padded
    for (int e = tid; e < 3072; e += 256) {
      int k = e >> 10, r = e & 1023, w = r >> 5, v = r & 31;
      float val = (v < 25 && w < 25) ? Al[k * 625 + v * 25 + w] : 0.f;
      atk[b * 3072 + e] = f2b(val);
    }
    // bias2d[n][c][w] = sum_k bc[k*64+c] * SA[k][w]
    for (int e = tid; e < 1600; e += 256) {
      int c = e / 25, w = e % 25;
      bias2d[b * 1600 + e] = bc[c] * SAl[w] + bc[64 + c] * SAl[25 + w] + bc[128 + c] * SAl[50 + w];
    }
  } else {
    // wT[c][r=k*64+ci] = conv_w[k*64+c][ci]
    for (int e = tid; e < 12288; e += 256) {
      int c = e / 192, r = e - c * 192, k = r >> 6, ci = r & 63;
      wt[e] = f2b(Wc[(k * 64 + c) * 64 + ci]);
    }
    // w2T[kt][co][ci] = tconv_w[co][ci][kt]
    for (int e = tid; e < 36864; e += 256) {
      int kt = e >> 12, rest = e & 4095, co = rest >> 6, ci = rest & 63;
      w2t[e] = f2b(tcw[(co * 64 + ci) * 9 + kt]);
    }
    if (tid < 64) {
      int c = tid;
      float i1 = g1[c] * rsqrtf(v1[c] + EPSf);
      float a1 = b1[c] - m1[c] * i1;
      float i2 = g2[c] * rsqrtf(v2[c] + EPSf);
      float a2 = b2[c] - m2[c] * i2 + tb[c] * i2;
      invadd[c] = i1; invadd[64 + c] = a1; invadd[128 + c] = i2; invadd[192 + c] = a2;
    }
  }
}

// zero the 100-row pads on both ends of each n's z' slab (zT rows: 7700/n)
__global__ __launch_bounds__(256) void kpad(u16* __restrict__ zT) {
  int i = blockIdx.x * 256 + threadIdx.x;     // 64 * 1600 chunks of 16B
  if (i >= 64 * 1600) return;
  int n = i / 1600, j = i - n * 1600;
  int row = (j < 800) ? (j >> 3) : (7600 + ((j - 800) >> 3));
  int c8 = j & 7;
  *(bf16x8*)(zT + ((size_t)n * 7700 + row) * 64 + c8 * 8) = (bf16x8){0,0,0,0,0,0,0,0};
}

// ---------------------------------------------------------------------------
// K1: fused GCN via MFMA. grid (50, 64), 4 waves, t-tile 6.
//  stage x->xs LDS (bf16, [ci][tpair][2][32v], swizzled), then per k:
//   stage1: D[w][ci] = atk[k] . xs   -> xa[tw][ci] LDS (swizzled)
//   stage2: acc[tw][co] += xa . wT[k]
//  epilogue: z' = relu(bn1(acc + bias2d)) -> zT (padded rows, [tv][c])
// ---------------------------------------------------------------------------
__global__ __launch_bounds__(256, 3) void k1_gcn(
    const float* __restrict__ x, const u16* __restrict__ atk, const u16* __restrict__ wt,
    const float* __restrict__ invadd, const float* __restrict__ bias2d,
    u16* __restrict__ zT)
{
  __shared__ __align__(16) u16 xs[64 * 6 * 32];   // 24576 B
  __shared__ __align__(16) u16 xa[160 * 64];      // 20480 B

  const int tid = threadIdx.x;
  const int tt = blockIdx.x, n = blockIdx.y;
  const int t0 = tt * 6;
  const int w = tid >> 6, l = tid & 63, lq = l & 15, g = l >> 4;

  // ---- coalesced x -> xs (bf16, v padded to 32; 128B rows hold 2 t's) ----
  for (int e = tid; e < 64 * 6 * 25; e += 256) {
    int ci = e / 150, r = e - ci * 150;
    int tl = r / 25, v = r - tl * 25;
    float xv = x[((size_t)(n * 64 + ci) * 300 + t0 + tl) * 25 + v];
    int byte = ((ci * 3 + (tl >> 1)) * 128 + (tl & 1) * 64 + v * 2) ^ ((ci & 7) << 4);
    *(u16*)((char*)xs + byte) = f2b(xv);
  }
  for (int e = tid; e < 64 * 6 * 7; e += 256) {
    int ci = e / 42, r = e - ci * 42;
    int tl = r / 7, v = 25 + (r - tl * 7);
    int byte = ((ci * 3 + (tl >> 1)) * 128 + (tl & 1) * 64 + v * 2) ^ ((ci & 7) << 4);
    *(u16*)((char*)xs + byte) = 0;
  }

  // hoisted fragments
  bf16x8 af[3][2];                       // atk A-frags [k][mt] (rows = w)
  #pragma unroll
  for (int k = 0; k < 3; ++k)
    #pragma unroll
    for (int mt = 0; mt < 2; ++mt)
      af[k][mt] = *(const bf16x8*)(atk + ((size_t)(n * 3 + k) * 32 + mt * 16 + lq) * 32 + g * 8);
  const int co0 = w * 16;
  bf16x8 wf[3][2];                       // wt B-frags [k][kc] (cols = co)
  #pragma unroll
  for (int k = 0; k < 3; ++k)
    #pragma unroll
    for (int kc = 0; kc < 2; ++kc)
      wf[k][kc] = *(const bf16x8*)(wt + (co0 + lq) * 192 + k * 64 + kc * 32 + g * 8);

  f32x4 acc[10];
  #pragma unroll
  for (int mi = 0; mi < 10; ++mi) acc[mi] = (f32x4){0.f, 0.f, 0.f, 0.f};

  const int ci0 = w * 16;
  const int cil = ci0 + lq;
  __syncthreads();

  #pragma unroll 1
  for (int k = 0; k < 3; ++k) {
    if (k) __syncthreads();
    // ---- stage 1: wave owns ci-tile ----
    #pragma unroll 1
    for (int tl = 0; tl < 6; ++tl) {
      const int bbyte = ((cil * 3 + (tl >> 1)) * 128 + (tl & 1) * 64 + g * 16) ^ ((cil & 7) << 4);
      const bf16x8 bx = *(const bf16x8*)((const char*)xs + bbyte);
      #pragma unroll
      for (int mt = 0; mt < 2; ++mt) {
        f32x4 d = {0.f, 0.f, 0.f, 0.f};
        d = __builtin_amdgcn_mfma_f32_16x16x32_bf16(af[k][mt], bx, d, 0, 0, 0);
        #pragma unroll
        for (int r = 0; r < 4; ++r) {
          const int wr = mt * 16 + g * 4 + r;
          if (wr < 25) {
            const int row = tl * 25 + wr;
            const int byte = (row * 128 + cil * 2) ^ ((row & 7) << 4);
            *(u16*)((char*)xa + byte) = f2b(d[r]);
          }
        }
      }
    }
    __syncthreads();
    // ---- stage 2: wave owns co-tile ----
    #pragma unroll
    for (int kc = 0; kc < 2; ++kc) {
      #pragma unroll 1
      for (int mi = 0; mi < 10; ++mi) {
        const int row = mi * 16 + lq;
        const int byte = (row * 128 + kc * 64 + g * 16) ^ ((row & 7) << 4);
        const bf16x8 a = *(const bf16x8*)((const char*)xa + byte);
        acc[mi] = __builtin_amdgcn_mfma_f32_16x16x32_bf16(a, wf[k][kc], acc[mi], 0, 0, 0);
      }
    }
  }

  // ---- epilogue: bias + bn1 + relu -> zT[tv][c] (rows offset by 100 pad) ----
  const float i1 = invadd[co0 + lq];
  const float a1 = invadd[64 + co0 + lq];
  const float* bb = bias2d + n * 1600 + (co0 + lq) * 25;
  #pragma unroll
  for (int mi = 0; mi < 10; ++mi) {
    #pragma unroll
    for (int r = 0; r < 4; ++r) {
      const int tw = mi * 16 + g * 4 + r;
      if (tw < 150) {
        const int wcol = tw % 25;                      // tt*150 % 25 == 0
        float z = (acc[mi][r] + bb[wcol]) * i1 + a1;
        zT[((size_t)n * 7700 + 100 + tt * 150 + tw) * 64 + co0 + lq] = f2b(fmaxf(z, 0.f));
      }
    }
  }
}

// ---------------------------------------------------------------------------
// K2: fused TCN via MFMA, no LDS. grid (59, 64), 4 waves; wave = 1 co-tile,
// weights in VGPR (prefetch next kt), z' B-frags direct from padded global.
// out = relu(bn2(conv) + x)
// ---------------------------------------------------------------------------
__global__ __launch_bounds__(256, 3) void k2_tcn(
    const u16* __restrict__ zT, const u16* __restrict__ w2t,
    const float* __restrict__ invadd, const float* __restrict__ x,
    float* __restrict__ out)
{
  const int tid = threadIdx.x;
  const int n = blockIdx.y;
  const int tvb = blockIdx.x * 128;
  const int w = tid >> 6, l = tid & 63, lq = l & 15, g = l >> 4;
  const int co0 = w * 16;

  const u16* zb = zT + ((size_t)n * 7700 + tvb) * 64;   // row = mi*16+lq + kt*25
  const u16* wb = w2t + (co0 + lq) * 64 + g * 8;

  bf16x8 a0 = *(const bf16x8*)(wb);
  bf16x8 a1 = *(const bf16x8*)(wb + 32);

  f32x4 acc[8];
  #pragma unroll
  for (int mi = 0; mi < 8; ++mi) acc[mi] = (f32x4){0.f, 0.f, 0.f, 0.f};

  #pragma unroll 1
  for (int kt = 0; kt < 9; ++kt) {
    bf16x8 p0, p1;
    if (kt < 8) {
      p0 = *(const bf16x8*)(wb + (kt + 1) * 4096);
      p1 = *(const bf16x8*)(wb + (kt + 1) * 4096 + 32);
    }
    const u16* zrow = zb + (kt * 25 + lq) * 64 + g * 8;
    #pragma unroll
    for (int mi = 0; mi < 8; ++mi) {
      const bf16x8 b0 = *(const bf16x8*)(zrow + mi * 1024);
      const bf16x8 b1 = *(const bf16x8*)(zrow + mi * 1024 + 32);
      acc[mi] = __builtin_amdgcn_mfma_f32_16x16x32_bf16(a0, b0, acc[mi], 0, 0, 0);
      acc[mi] = __builtin_amdgcn_mfma_f32_16x16x32_bf16(a1, b1, acc[mi], 0, 0, 0);
    }
    a0 = p0; a1 = p1;
  }

  float i2[4], a2[4];
  #pragma unroll
  for (int r = 0; r < 4; ++r) {
    const int co = co0 + g * 4 + r;
    i2[r] = invadd[128 + co];
    a2[r] = invadd[192 + co];
  }
  #pragma unroll
  for (int mi = 0; mi < 8; ++mi) {
    const int tv = tvb + mi * 16 + lq;
    if (tv < 7500) {
      #pragma unroll
      for (int r = 0; r < 4; ++r) {
        const int co = co0 + g * 4 + r;
        const size_t idx = (size_t)(n * 64 + co) * 7500 + tv;
        out[idx] = fmaxf(acc[mi][r] * i2[r] + a2[r] + x[idx], 0.f);
      }
    }
  }
}

__global__ void k3_copyA(const float* __restrict__ A, float* __restrict__ outA) {
  int i = blockIdx.x * 256 + threadIdx.x;
  if (i < 64 * 3 * 25 * 25) outA[i] = A[i];
}

} // namespace

extern "C" void kernel_launch(void* const* d_in, const int* in_sizes, int n_in,
                              void* d_out, int out_size, void* d_ws, size_t ws_size,
                              hipStream_t stream)
{
  const float* x  = (const float*)d_in[0];
  const float* A  = (const float*)d_in[1];
  const float* Wc = (const float*)d_in[2];
  const float* bc = (const float*)d_in[3];
  const float* g1 = (const float*)d_in[4];
  const float* b1 = (const float*)d_in[5];
  const float* m1 = (const float*)d_in[6];
  const float* v1 = (const float*)d_in[7];
  const float* tw = (const float*)d_in[8];
  const float* tb = (const float*)d_in[9];
  const float* g2 = (const float*)d_in[10];
  const float* b2 = (const float*)d_in[11];
  const float* m2 = (const float*)d_in[12];
  const float* v2 = (const float*)d_in[13];
  float* out = (float*)d_out;

  char* ws = (char*)d_ws;
  u16*   zT     = (u16*)(ws);                        // 64*7700*64*2 = 63,078,400 B
  u16*   atk    = (u16*)(ws + 63078400);             //    393,216 B
  u16*   wt     = (u16*)(ws + 63471616);             //     24,576 B
  u16*   w2t    = (u16*)(ws + 63496192);             //     73,728 B
  float* invadd = (float*)(ws + 63569920);           //      1,024 B
  float* bias2d = (float*)(ws + 63570944);           //    409,600 B

  prep<<<dim3(65), dim3(256), 0, stream>>>(A, Wc, bc, g1, b1, m1, v1, tw, tb,
                                           g2, b2, m2, v2, atk, wt, w2t, invadd, bias2d);
  kpad<<<dim3(400), dim3(256), 0, stream>>>(zT);
  k1_gcn<<<dim3(50, 64), dim3(256), 0, stream>>>(x, atk, wt, invadd, bias2d, zT);
  k2_tcn<<<dim3(59, 64), dim3(256), 0, stream>>>(zT, w2t, invadd, x, out);
  k3_copyA<<<dim3((120000 + 255) / 256), dim3(256), 0, stream>>>(A, out + 30720000);
}

// Round 4
// 740.284 us; speedup vs baseline: 1.0089x; 1.0089x over previous
//
#include <hip/hip_runtime.h>
#include <hip/hip_bf16.h>

typedef float f32x4 __attribute__((ext_vector_type(4)));
typedef short bf16x8 __attribute__((ext_vector_type(8)));
typedef unsigned short u16;

namespace {

constexpr float EPSf = 1e-5f;

__device__ __forceinline__ u16 f2b(float f) {
  __hip_bfloat16 h = __float2bfloat16(f);
  return *(u16*)&h;
}

// ---------------------------------------------------------------------------
// prep: blocks 0..63 -> per-n AT (padded, transposed, bf16) + bias2d table
//       block 64     -> wT, w2T, folded BN coefficients
// ---------------------------------------------------------------------------
__global__ __launch_bounds__(256) void prep(
    const float* __restrict__ A, const float* __restrict__ Wc, const float* __restrict__ bc,
    const float* __restrict__ g1, const float* __restrict__ b1,
    const float* __restrict__ m1, const float* __restrict__ v1,
    const float* __restrict__ tcw, const float* __restrict__ tb,
    const float* __restrict__ g2, const float* __restrict__ b2,
    const float* __restrict__ m2, const float* __restrict__ v2,
    u16* __restrict__ atk, u16* __restrict__ wt, u16* __restrict__ w2t,
    float* __restrict__ invadd, float* __restrict__ bias2d)
{
  const int b = blockIdx.x, tid = threadIdx.x;
  if (b < 64) {
    __shared__ float Al[1875];
    __shared__ float SAl[75];
    const float* An = A + b * 1875;
    for (int e = tid; e < 1875; e += 256) Al[e] = An[e];
    __syncthreads();
    if (tid < 75) {
      int k = tid / 25, w = tid % 25;
      float s = 0.f;
      for (int v = 0; v < 25; ++v) s += Al[k * 625 + v * 25 + w];
      SAl[tid] = s;
    }
    __syncthreads();
    // AT[k][w(32)][v(32)] = A[n][k][v][w], zero-padded
    for (int e = tid; e < 3072; e += 256) {
      int k = e >> 10, r = e & 1023, w = r >> 5, v = r & 31;
      float val = (v < 25 && w < 25) ? Al[k * 625 + v * 25 + w] : 0.f;
      atk[b * 3072 + e] = f2b(val);
    }
    // bias2d[n][c][w] = sum_k bc[k*64+c] * SA[k][w]
    for (int e = tid; e < 1600; e += 256) {
      int c = e / 25, w = e % 25;
      bias2d[b * 1600 + e] = bc[c] * SAl[w] + bc[64 + c] * SAl[25 + w] + bc[128 + c] * SAl[50 + w];
    }
  } else {
    // wT[c][r=k*64+ci] = conv_w[k*64+c][ci]
    for (int e = tid; e < 12288; e += 256) {
      int c = e / 192, r = e - c * 192, k = r >> 6, ci = r & 63;
      wt[e] = f2b(Wc[(k * 64 + c) * 64 + ci]);
    }
    // w2T[kt][co][ci] = tconv_w[co][ci][kt]
    for (int e = tid; e < 36864; e += 256) {
      int kt = e >> 12, rest = e & 4095, co = rest >> 6, ci = rest & 63;
      w2t[e] = f2b(tcw[(co * 64 + ci) * 9 + kt]);
    }
    if (tid < 64) {
      int c = tid;
      float i1 = g1[c] * rsqrtf(v1[c] + EPSf);
      float a1 = b1[c] - m1[c] * i1;
      float i2 = g2[c] * rsqrtf(v2[c] + EPSf);
      float a2 = b2[c] - m2[c] * i2 + tb[c] * i2;
      invadd[c] = i1; invadd[64 + c] = a1; invadd[128 + c] = i2; invadd[192 + c] = a2;
    }
  }
}

// zero the 100-row pads on both ends of each n's z' slab (zT rows: 7700/n)
__global__ __launch_bounds__(256) void kpad(u16* __restrict__ zT) {
  int i = blockIdx.x * 256 + threadIdx.x;     // 64 * 1600 chunks of 16B
  if (i >= 64 * 1600) return;
  int n = i / 1600, j = i - n * 1600;
  int row = (j < 800) ? (j >> 3) : (7600 + ((j - 800) >> 3));
  int c8 = j & 7;
  *(bf16x8*)(zT + ((size_t)n * 7700 + row) * 64 + c8 * 8) = (bf16x8){0,0,0,0,0,0,0,0};
}

// ---------------------------------------------------------------------------
// K1: fused GCN via MFMA. grid (50, 64), 4 waves, t-tile 6.
//  stage x->xs LDS (bf16, swizzled), then per k:
//   stage1: D[w][ci] = atk[k] . xs   -> xa[tw][ci] LDS (swizzled)
//   stage2: acc[tw][co] += xa . wT[k]
//  epilogue: bn1+relu -> LDS transpose (reuse xa) -> coalesced 128B zT stores
// ---------------------------------------------------------------------------
__global__ __launch_bounds__(256, 3) void k1_gcn(
    const float* __restrict__ x, const u16* __restrict__ atk, const u16* __restrict__ wt,
    const float* __restrict__ invadd, const float* __restrict__ bias2d,
    u16* __restrict__ zT)
{
  __shared__ __align__(16) u16 xs[64 * 6 * 32];   // 24576 B
  __shared__ __align__(16) u16 xa[160 * 64];      // 20480 B (stage-1 out, then z-store tile)

  const int tid = threadIdx.x;
  const int tt = blockIdx.x, n = blockIdx.y;
  const int t0 = tt * 6;
  const int w = tid >> 6, l = tid & 63, lq = l & 15, g = l >> 4;

  // ---- coalesced x -> xs (bf16, v padded to 32; 128B rows hold 2 t's) ----
  for (int e = tid; e < 64 * 6 * 25; e += 256) {
    int ci = e / 150, r = e - ci * 150;
    int tl = r / 25, v = r - tl * 25;
    float xv = x[((size_t)(n * 64 + ci) * 300 + t0 + tl) * 25 + v];
    int byte = ((ci * 3 + (tl >> 1)) * 128 + (tl & 1) * 64 + v * 2) ^ ((ci & 7) << 4);
    *(u16*)((char*)xs + byte) = f2b(xv);
  }
  for (int e = tid; e < 64 * 6 * 7; e += 256) {
    int ci = e / 42, r = e - ci * 42;
    int tl = r / 7, v = 25 + (r - tl * 7);
    int byte = ((ci * 3 + (tl >> 1)) * 128 + (tl & 1) * 64 + v * 2) ^ ((ci & 7) << 4);
    *(u16*)((char*)xs + byte) = 0;
  }

  // hoisted fragments
  bf16x8 af[3][2];                       // atk A-frags [k][mt] (rows = w-vertex)
  #pragma unroll
  for (int k = 0; k < 3; ++k)
    #pragma unroll
    for (int mt = 0; mt < 2; ++mt)
      af[k][mt] = *(const bf16x8*)(atk + ((size_t)(n * 3 + k) * 32 + mt * 16 + lq) * 32 + g * 8);
  const int co0 = w * 16;
  bf16x8 wf[3][2];                       // wt B-frags [k][kc] (cols = co)
  #pragma unroll
  for (int k = 0; k < 3; ++k)
    #pragma unroll
    for (int kc = 0; kc < 2; ++kc)
      wf[k][kc] = *(const bf16x8*)(wt + (co0 + lq) * 192 + k * 64 + kc * 32 + g * 8);

  f32x4 acc[10];
  #pragma unroll
  for (int mi = 0; mi < 10; ++mi) acc[mi] = (f32x4){0.f, 0.f, 0.f, 0.f};

  const int ci0 = w * 16;
  const int cil = ci0 + lq;
  __syncthreads();

  #pragma unroll 1
  for (int k = 0; k < 3; ++k) {
    if (k) __syncthreads();
    // ---- stage 1: wave owns ci-tile ----
    #pragma unroll 1
    for (int tl = 0; tl < 6; ++tl) {
      const int bbyte = ((cil * 3 + (tl >> 1)) * 128 + (tl & 1) * 64 + g * 16) ^ ((cil & 7) << 4);
      const bf16x8 bx = *(const bf16x8*)((const char*)xs + bbyte);
      #pragma unroll
      for (int mt = 0; mt < 2; ++mt) {
        f32x4 d = {0.f, 0.f, 0.f, 0.f};
        d = __builtin_amdgcn_mfma_f32_16x16x32_bf16(af[k][mt], bx, d, 0, 0, 0);
        #pragma unroll
        for (int r = 0; r < 4; ++r) {
          const int wr = mt * 16 + g * 4 + r;
          if (wr < 25) {
            const int row = tl * 25 + wr;
            const int byte = (row * 128 + cil * 2) ^ ((row & 7) << 4);
            *(u16*)((char*)xa + byte) = f2b(d[r]);
          }
        }
      }
    }
    __syncthreads();
    // ---- stage 2: wave owns co-tile ----
    #pragma unroll
    for (int kc = 0; kc < 2; ++kc) {
      #pragma unroll 1
      for (int mi = 0; mi < 10; ++mi) {
        const int row = mi * 16 + lq;
        const int byte = (row * 128 + kc * 64 + g * 16) ^ ((row & 7) << 4);
        const bf16x8 a = *(const bf16x8*)((const char*)xa + byte);
        acc[mi] = __builtin_amdgcn_mfma_f32_16x16x32_bf16(a, wf[k][kc], acc[mi], 0, 0, 0);
      }
    }
  }

  // ---- epilogue: bn1+relu, transpose via LDS (reuse xa), coalesced stores ----
  const float i1 = invadd[co0 + lq];
  const float a1 = invadd[64 + co0 + lq];
  const float* bb = bias2d + n * 1600 + (co0 + lq) * 25;
  __syncthreads();                       // all stage-2 xa reads done; reuse as z-tile
  #pragma unroll
  for (int mi = 0; mi < 10; ++mi) {
    #pragma unroll
    for (int r = 0; r < 4; ++r) {
      const int tw = mi * 16 + g * 4 + r;      // 0..159 (150..159 dead rows)
      const int wcol = tw % 25;
      float z = (acc[mi][r] + bb[wcol]) * i1 + a1;
      const int byte = (tw * 128 + (co0 + lq) * 2) ^ ((tw & 7) << 4);
      *(u16*)((char*)xa + byte) = f2b(fmaxf(z, 0.f));
    }
  }
  __syncthreads();
  // 8 lanes x 16B = one full 128B zT row; fully coalesced global stores
  for (int e = tid; e < 150 * 8; e += 256) {
    const int row = e >> 3, c8 = e & 7;
    const int byte = (row * 128 + c8 * 16) ^ ((row & 7) << 4);
    const bf16x8 vz = *(const bf16x8*)((const char*)xa + byte);
    *(bf16x8*)(zT + ((size_t)n * 7700 + 100 + tt * 150 + row) * 64 + c8 * 8) = vz;
  }
}

// ---------------------------------------------------------------------------
// K2: fused TCN via MFMA, no LDS. grid (59, 64), 4 waves; wave = 1 co-tile,
// weights in VGPR (prefetch next kt), z' B-frags direct from padded global.
// out = relu(bn2(conv) + x)
// ---------------------------------------------------------------------------
__global__ __launch_bounds__(256, 3) void k2_tcn(
    const u16* __restrict__ zT, const u16* __restrict__ w2t,
    const float* __restrict__ invadd, const float* __restrict__ x,
    float* __restrict__ out)
{
  const int tid = threadIdx.x;
  const int n = blockIdx.y;
  const int tvb = blockIdx.x * 128;
  const int w = tid >> 6, l = tid & 63, lq = l & 15, g = l >> 4;
  const int co0 = w * 16;

  const u16* zb = zT + ((size_t)n * 7700 + tvb) * 64;   // row = mi*16+lq + kt*25
  const u16* wb = w2t + (co0 + lq) * 64 + g * 8;

  bf16x8 a0 = *(const bf16x8*)(wb);
  bf16x8 a1 = *(const bf16x8*)(wb + 32);

  f32x4 acc[8];
  #pragma unroll
  for (int mi = 0; mi < 8; ++mi) acc[mi] = (f32x4){0.f, 0.f, 0.f, 0.f};

  #pragma unroll 1
  for (int kt = 0; kt < 9; ++kt) {
    bf16x8 p0, p1;
    if (kt < 8) {
      p0 = *(const bf16x8*)(wb + (kt + 1) * 4096);
      p1 = *(const bf16x8*)(wb + (kt + 1) * 4096 + 32);
    }
    const u16* zrow = zb + (kt * 25 + lq) * 64 + g * 8;
    #pragma unroll
    for (int mi = 0; mi < 8; ++mi) {
      const bf16x8 b0 = *(const bf16x8*)(zrow + mi * 1024);
      const bf16x8 b1 = *(const bf16x8*)(zrow + mi * 1024 + 32);
      acc[mi] = __builtin_amdgcn_mfma_f32_16x16x32_bf16(a0, b0, acc[mi], 0, 0, 0);
      acc[mi] = __builtin_amdgcn_mfma_f32_16x16x32_bf16(a1, b1, acc[mi], 0, 0, 0);
    }
    a0 = p0; a1 = p1;
  }

  float i2[4], a2[4];
  #pragma unroll
  for (int r = 0; r < 4; ++r) {
    const int co = co0 + g * 4 + r;
    i2[r] = invadd[128 + co];
    a2[r] = invadd[192 + co];
  }
  #pragma unroll
  for (int mi = 0; mi < 8; ++mi) {
    const int tv = tvb + mi * 16 + lq;
    if (tv < 7500) {
      #pragma unroll
      for (int r = 0; r < 4; ++r) {
        const int co = co0 + g * 4 + r;
        const size_t idx = (size_t)(n * 64 + co) * 7500 + tv;
        out[idx] = fmaxf(acc[mi][r] * i2[r] + a2[r] + x[idx], 0.f);
      }
    }
  }
}

__global__ void k3_copyA(const float* __restrict__ A, float* __restrict__ outA) {
  int i = blockIdx.x * 256 + threadIdx.x;
  if (i < 64 * 3 * 25 * 25) outA[i] = A[i];
}

} // namespace

extern "C" void kernel_launch(void* const* d_in, const int* in_sizes, int n_in,
                              void* d_out, int out_size, void* d_ws, size_t ws_size,
                              hipStream_t stream)
{
  const float* x  = (const float*)d_in[0];
  const float* A  = (const float*)d_in[1];
  const float* Wc = (const float*)d_in[2];
  const float* bc = (const float*)d_in[3];
  const float* g1 = (const float*)d_in[4];
  const float* b1 = (const float*)d_in[5];
  const float* m1 = (const float*)d_in[6];
  const float* v1 = (const float*)d_in[7];
  const float* tw = (const float*)d_in[8];
  const float* tb = (const float*)d_in[9];
  const float* g2 = (const float*)d_in[10];
  const float* b2 = (const float*)d_in[11];
  const float* m2 = (const float*)d_in[12];
  const float* v2 = (const float*)d_in[13];
  float* out = (float*)d_out;

  char* ws = (char*)d_ws;
  u16*   zT     = (u16*)(ws);                        // 64*7700*64*2 = 63,078,400 B
  u16*   atk    = (u16*)(ws + 63078400);             //    393,216 B
  u16*   wt     = (u16*)(ws + 63471616);             //     24,576 B
  u16*   w2t    = (u16*)(ws + 63496192);             //     73,728 B
  float* invadd = (float*)(ws + 63569920);           //      1,024 B
  float* bias2d = (float*)(ws + 63570944);           //    409,600 B

  prep<<<dim3(65), dim3(256), 0, stream>>>(A, Wc, bc, g1, b1, m1, v1, tw, tb,
                                           g2, b2, m2, v2, atk, wt, w2t, invadd, bias2d);
  kpad<<<dim3(400), dim3(256), 0, stream>>>(zT);
  k1_gcn<<<dim3(50, 64), dim3(256), 0, stream>>>(x, atk, wt, invadd, bias2d, zT);
  k2_tcn<<<dim3(59, 64), dim3(256), 0, stream>>>(zT, w2t, invadd, x, out);
  k3_copyA<<<dim3((120000 + 255) / 256), dim3(256), 0, stream>>>(A, out + 30720000);
}

// Round 5
// 240.894 us; speedup vs baseline: 3.1003x; 3.0731x over previous
//
#include <hip/hip_runtime.h>

typedef float f32x4 __attribute__((ext_vector_type(4)));
typedef short bf16x8 __attribute__((ext_vector_type(8)));
typedef unsigned short u16;

namespace {

constexpr int Nn = 64, Tt = 300, Vv = 25;
constexpr float EPSf = 1e-5f;

__device__ __forceinline__ u16 f2bu(float f) {
  union { float f; unsigned int i; } c; c.f = f;
  unsigned int r = c.i + 0x7fffu + ((c.i >> 16) & 1u);   // RNE
  return (u16)(r >> 16);
}

// ---------------------------------------------------------------------------
// prep: blocks 0..63 -> per-n AT (padded, transposed, bf16) + bias2d table
//       block 64     -> wT + folded BN coefficients
//       blocks 65..73 -> w2T for kt = b-65
// ---------------------------------------------------------------------------
__global__ __launch_bounds__(256) void prep(
    const float* __restrict__ A, const float* __restrict__ Wc, const float* __restrict__ bc,
    const float* __restrict__ g1, const float* __restrict__ b1,
    const float* __restrict__ m1, const float* __restrict__ v1,
    const float* __restrict__ tcw, const float* __restrict__ tb,
    const float* __restrict__ g2, const float* __restrict__ b2,
    const float* __restrict__ m2, const float* __restrict__ v2,
    u16* __restrict__ atk, u16* __restrict__ wt, u16* __restrict__ w2t,
    float* __restrict__ invadd, float* __restrict__ bias2d)
{
  const int b = blockIdx.x, tid = threadIdx.x;
  if (b < 64) {
    __shared__ float Al[1875];
    __shared__ float SAl[75];
    const float* An = A + b * 1875;
    for (int e = tid; e < 1875; e += 256) Al[e] = An[e];
    __syncthreads();
    if (tid < 75) {
      int k = tid / 25, w = tid % 25;
      float s = 0.f;
      for (int v = 0; v < 25; ++v) s += Al[k * 625 + v * 25 + w];
      SAl[tid] = s;
    }
    __syncthreads();
    // AT[k][w(32)][v(32)] = A[n][k][v][w], zero-padded
    for (int e = tid; e < 3072; e += 256) {
      int k = e >> 10, r = e & 1023, w = r >> 5, v = r & 31;
      float val = (v < 25 && w < 25) ? Al[k * 625 + v * 25 + w] : 0.f;
      atk[b * 3072 + e] = f2bu(val);
    }
    // bias2d[n][c][w] = sum_k bc[k*64+c] * SA[k][w]
    for (int e = tid; e < 1600; e += 256) {
      int c = e / 25, w = e % 25;
      bias2d[b * 1600 + e] = bc[c] * SAl[w] + bc[64 + c] * SAl[25 + w] + bc[128 + c] * SAl[50 + w];
    }
  } else if (b == 64) {
    // wT[c][r=k*64+ci] = conv_w[k*64+c][ci]
    for (int e = tid; e < 12288; e += 256) {
      int c = e / 192, r = e - c * 192, k = r >> 6, ci = r & 63;
      wt[e] = f2bu(Wc[(k * 64 + c) * 64 + ci]);
    }
    if (tid < 64) {
      int c = tid;
      float i1 = g1[c] * rsqrtf(v1[c] + EPSf);
      float a1 = b1[c] - m1[c] * i1;
      float i2 = g2[c] * rsqrtf(v2[c] + EPSf);
      float a2 = b2[c] - m2[c] * i2 + tb[c] * i2;
      invadd[c] = i1; invadd[64 + c] = a1; invadd[128 + c] = i2; invadd[192 + c] = a2;
    }
  } else {
    // w2T[kt][co][ci] = tconv_w[co][ci][kt], one kt per block
    const int kt = b - 65;
    for (int i = tid; i < 4096; i += 256) {
      int co = i >> 6, ci = i & 63;
      w2t[kt * 4096 + i] = f2bu(tcw[(co * 64 + ci) * 9 + kt]);
    }
  }
}

// ---------------------------------------------------------------------------
// K1: fused GCN via MFMA. grid (50, 64), 256 threads = 4 waves, 6-t tile.
// stage1: xaT[tw<150][r=k*64+ci]  (LDS, swizzled)   = sum_v x * A
// stage2: z'T[tv][c] (global bf16) = relu(bn1(wT . xaT + bias2d))
// Changes vs R2: stage-2 weight frags fully preloaded to VGPR; stage-1
// x-loads depth-1 prefetched (breaks serial load->mfma chain).
// ---------------------------------------------------------------------------
__global__ __launch_bounds__(256) void k1_gcn(
    const float* __restrict__ x, const u16* __restrict__ atk, const u16* __restrict__ wt,
    const float* __restrict__ invadd, const float* __restrict__ bias2d,
    u16* __restrict__ zT)
{
  __shared__ __align__(16) u16 xaT[160 * 192];
  __shared__ float bias_l[1600];

  const int tid = threadIdx.x;
  const int tt = blockIdx.x, n = blockIdx.y;
  const int t0 = tt * 6;
  const int w = tid >> 6, l = tid & 63, lq = l & 15, g = l >> 4;

  for (int e = tid; e < 1600; e += 256) bias_l[e] = bias2d[n * 1600 + e];
  for (int e = tid; e < 10 * 192; e += 256) xaT[150 * 192 + e] = 0;  // tail rows -> 0

  // hoisted stage-1 B-frags: B[v][w] stored AT[w][v]
  bf16x8 Bf[3][2];
  #pragma unroll
  for (int k = 0; k < 3; ++k)
    #pragma unroll
    for (int nt = 0; nt < 2; ++nt)
      Bf[k][nt] = *(const bf16x8*)(atk + ((size_t)(n * 3 + k) * 32 + nt * 16 + lq) * 32 + g * 8);

  // preloaded stage-2 A-frags (weights): removes global loads from acc loop
  bf16x8 Af[6][4];
  #pragma unroll
  for (int kc = 0; kc < 6; ++kc)
    #pragma unroll
    for (int ct = 0; ct < 4; ++ct)
      Af[kc][ct] = *(const bf16x8*)(wt + (ct * 16 + lq) * 192 + kc * 32 + g * 8);

  // ---- stage 1: 24 M-tiles (6 t x 4 ci-tiles), wave w takes mt = w+4i ----
  f32x4 xc0, xc1;
  {
    const int mt = w;
    const int tl = mt >> 2, ci0 = (mt & 3) << 4;
    const float* xr = x + ((size_t)(n * 64 + ci0 + lq) * Tt + t0 + tl) * Vv;
    __builtin_memcpy(&xc0, xr + g * 8, 16);
    __builtin_memcpy(&xc1, xr + g * 8 + 4, 16);
  }
  #pragma unroll 1
  for (int i = 0; i < 6; ++i) {
    f32x4 xn0, xn1;
    if (i < 5) {
      const int mtn = w + 4 * (i + 1);
      const int tln = mtn >> 2, ci0n = (mtn & 3) << 4;
      const float* xrn = x + ((size_t)(n * 64 + ci0n + lq) * Tt + t0 + tln) * Vv;
      __builtin_memcpy(&xn0, xrn + g * 8, 16);
      __builtin_memcpy(&xn1, xrn + g * 8 + 4, 16);
    }
    const int mt = w + 4 * i;
    const int tl = mt >> 2, ci0 = (mt & 3) << 4;
    bf16x8 a;
    if (g < 3) {
      a[0] = (short)f2bu(xc0[0]); a[1] = (short)f2bu(xc0[1]);
      a[2] = (short)f2bu(xc0[2]); a[3] = (short)f2bu(xc0[3]);
      a[4] = (short)f2bu(xc1[0]); a[5] = (short)f2bu(xc1[1]);
      a[6] = (short)f2bu(xc1[2]); a[7] = (short)f2bu(xc1[3]);
    } else {
      a[0] = (short)f2bu(xc0[0]);     // element v=24
      a[1] = 0; a[2] = 0; a[3] = 0; a[4] = 0; a[5] = 0; a[6] = 0; a[7] = 0;
    }
    #pragma unroll
    for (int k = 0; k < 3; ++k)
      #pragma unroll
      for (int nt = 0; nt < 2; ++nt) {
        f32x4 acc = {0.f, 0.f, 0.f, 0.f};
        acc = __builtin_amdgcn_mfma_f32_16x16x32_bf16(a, Bf[k][nt], acc, 0, 0, 0);
        const int wcol = nt * 16 + lq;
        if (wcol < 25) {
          const int twl = tl * 25 + wcol;
          ushort4 s;
          s.x = f2bu(acc[0]); s.y = f2bu(acc[1]); s.z = f2bu(acc[2]); s.w = f2bu(acc[3]);
          const int byte = twl * 384 + ((k * 128 + ci0 * 2 + g * 8) ^ ((twl & 7) << 4));
          *(ushort4*)((char*)xaT + byte) = s;
        }
      }
    xc0 = xn0; xc1 = xn1;
  }
  __syncthreads();

  // ---- stage 2: D[c][tw] ; waves split the 10 tw-tiles {w, w+4, w+8} ----
  f32x4 acc2[3][4];
  #pragma unroll
  for (int ni = 0; ni < 3; ++ni)
    #pragma unroll
    for (int ct = 0; ct < 4; ++ct) acc2[ni][ct] = (f32x4){0.f, 0.f, 0.f, 0.f};
  const int nvalid = (w < 2) ? 3 : 2;

  #pragma unroll
  for (int kc = 0; kc < 6; ++kc) {
    #pragma unroll
    for (int ni = 0; ni < 3; ++ni) {
      if (ni < nvalid) {
        const int row = (w + 4 * ni) * 16 + lq;
        const int byte = row * 384 + ((kc * 64 + g * 16) ^ ((row & 7) << 4));
        const bf16x8 Bv = *(const bf16x8*)((const char*)xaT + byte);
        #pragma unroll
        for (int ct = 0; ct < 4; ++ct)
          acc2[ni][ct] = __builtin_amdgcn_mfma_f32_16x16x32_bf16(Af[kc][ct], Bv, acc2[ni][ct], 0, 0, 0);
      }
    }
  }

  #pragma unroll
  for (int ni = 0; ni < 3; ++ni) {
    if (ni < nvalid) {
      const int twl = (w + 4 * ni) * 16 + lq;
      if (twl < 150) {
        const int wcol = twl % 25;
        const int tvg = tt * 150 + twl;
        #pragma unroll
        for (int ct = 0; ct < 4; ++ct) {
          const int c0 = ct * 16 + g * 4;
          const f32x4 iv = *(const f32x4*)(invadd + c0);
          const f32x4 av = *(const f32x4*)(invadd + 64 + c0);
          ushort4 s;
          float z0 = (acc2[ni][ct][0] + bias_l[(c0 + 0) * 25 + wcol]) * iv[0] + av[0];
          float z1 = (acc2[ni][ct][1] + bias_l[(c0 + 1) * 25 + wcol]) * iv[1] + av[1];
          float z2 = (acc2[ni][ct][2] + bias_l[(c0 + 2) * 25 + wcol]) * iv[2] + av[2];
          float z3 = (acc2[ni][ct][3] + bias_l[(c0 + 3) * 25 + wcol]) * iv[3] + av[3];
          s.x = f2bu(fmaxf(z0, 0.f)); s.y = f2bu(fmaxf(z1, 0.f));
          s.z = f2bu(fmaxf(z2, 0.f)); s.w = f2bu(fmaxf(z3, 0.f));
          *(ushort4*)(zT + ((size_t)n * 7500 + tvg) * 64 + c0) = s;
        }
      }
    }
  }
}

// ---------------------------------------------------------------------------
// K2: fused TCN via MFMA. grid (25, 64), 256 threads = 4 waves, 12-t tile.
// window z'T rows staged swizzled in LDS; 18 K-steps with depth-1 register
// prefetch of the 4 weight B-frags (removes per-step global-load stall).
// out = relu(bn2(conv) + x), coalesced float4.
// ---------------------------------------------------------------------------
__global__ __launch_bounds__(256) void k2_tcn(
    const u16* __restrict__ zT, const u16* __restrict__ w2t,
    const float* __restrict__ invadd, const float* __restrict__ x,
    float* __restrict__ out)
{
  __shared__ __align__(16) u16 win[504 * 64];

  const int tid = threadIdx.x;
  const int tt = blockIdx.x, n = blockIdx.y;
  const int t0 = tt * 12;
  const int w = tid >> 6, l = tid & 63, lq = l & 15, g = l >> 4;
  const int tvbase = t0 * 25 - 100;

  for (int f = tid; f < 504 * 8; f += 256) {
    const int lrow = f >> 3, c16 = f & 7;
    const int tv = tvbase + lrow;
    bf16x8 val = {0, 0, 0, 0, 0, 0, 0, 0};
    if (tv >= 0 && tv < 7500)
      val = *(const bf16x8*)(zT + ((size_t)n * 7500 + tv) * 64 + c16 * 8);
    const int byte = lrow * 128 + ((c16 * 16) ^ ((lrow & 7) << 4));
    *(bf16x8*)((char*)win + byte) = val;
  }
  __syncthreads();

  f32x4 acc[5][4];
  #pragma unroll
  for (int mi = 0; mi < 5; ++mi)
    #pragma unroll
    for (int nt = 0; nt < 4; ++nt) acc[mi][nt] = (f32x4){0.f, 0.f, 0.f, 0.f};
  const int nmt = (w < 3) ? 5 : 4;      // 19 M-tiles over 4 waves

  bf16x8 Bcur[4], Bnxt[4];
  #pragma unroll
  for (int nt = 0; nt < 4; ++nt)
    Bcur[nt] = *(const bf16x8*)(w2t + (size_t)(nt * 16 + lq) * 64 + g * 8);

  #pragma unroll 1
  for (int s = 0; s < 18; ++s) {
    const int kt = s >> 1, kc = s & 1;
    if (s < 17) {
      const int ktn = (s + 1) >> 1, kcn = (s + 1) & 1;
      #pragma unroll
      for (int nt = 0; nt < 4; ++nt)
        Bnxt[nt] = *(const bf16x8*)(w2t + (size_t)(ktn * 64 + nt * 16 + lq) * 64 + kcn * 32 + g * 8);
    }
    #pragma unroll
    for (int mi = 0; mi < 5; ++mi) {
      if (mi < nmt) {
        const int lrow = (w + 4 * mi) * 16 + lq + kt * 25;
        const int byte = lrow * 128 + ((kc * 64 + g * 16) ^ ((lrow & 7) << 4));
        const bf16x8 Av = *(const bf16x8*)((const char*)win + byte);
        #pragma unroll
        for (int nt = 0; nt < 4; ++nt)
          acc[mi][nt] = __builtin_amdgcn_mfma_f32_16x16x32_bf16(Av, Bcur[nt], acc[mi][nt], 0, 0, 0);
      }
    }
    if (s < 17) {
      #pragma unroll
      for (int nt = 0; nt < 4; ++nt) Bcur[nt] = Bnxt[nt];
    }
  }

  #pragma unroll
  for (int mi = 0; mi < 5; ++mi) {
    if (mi < nmt) {
      const int tvl0 = (w + 4 * mi) * 16 + g * 4;
      if (tvl0 < 300) {
        #pragma unroll
        for (int nt = 0; nt < 4; ++nt) {
          const int co = nt * 16 + lq;
          const float i2 = invadd[128 + co], a2 = invadd[192 + co];
          const size_t base = (size_t)(n * 64 + co) * 7500 + t0 * 25 + tvl0;
          const f32x4 xv = *(const f32x4*)(x + base);
          f32x4 o;
          #pragma unroll
          for (int r = 0; r < 4; ++r)
            o[r] = fmaxf(acc[mi][nt][r] * i2 + a2 + xv[r], 0.f);
          *(f32x4*)(out + base) = o;
        }
      }
    }
  }
}

__global__ void k3_copyA(const float* __restrict__ A, float* __restrict__ outA) {
  int i = blockIdx.x * 256 + threadIdx.x;
  if (i < 64 * 3 * 25 * 25) outA[i] = A[i];
}

} // namespace

extern "C" void kernel_launch(void* const* d_in, const int* in_sizes, int n_in,
                              void* d_out, int out_size, void* d_ws, size_t ws_size,
                              hipStream_t stream)
{
  const float* x  = (const float*)d_in[0];
  const float* A  = (const float*)d_in[1];
  const float* Wc = (const float*)d_in[2];
  const float* bc = (const float*)d_in[3];
  const float* g1 = (const float*)d_in[4];
  const float* b1 = (const float*)d_in[5];
  const float* m1 = (const float*)d_in[6];
  const float* v1 = (const float*)d_in[7];
  const float* tw = (const float*)d_in[8];
  const float* tb = (const float*)d_in[9];
  const float* g2 = (const float*)d_in[10];
  const float* b2 = (const float*)d_in[11];
  const float* m2 = (const float*)d_in[12];
  const float* v2 = (const float*)d_in[13];
  float* out = (float*)d_out;

  char* ws = (char*)d_ws;
  u16*   zT     = (u16*)(ws);                        // 61,440,000 B
  u16*   atk    = (u16*)(ws + 61440000);             //    393,216 B
  u16*   wt     = (u16*)(ws + 61833216);             //     24,576 B
  u16*   w2t    = (u16*)(ws + 61857792);             //     73,728 B
  float* invadd = (float*)(ws + 61931520);           //      1,024 B
  float* bias2d = (float*)(ws + 61932544);           //    409,600 B

  prep<<<dim3(74), dim3(256), 0, stream>>>(A, Wc, bc, g1, b1, m1, v1, tw, tb,
                                           g2, b2, m2, v2, atk, wt, w2t, invadd, bias2d);
  k1_gcn<<<dim3(50, 64), dim3(256), 0, stream>>>(x, atk, wt, invadd, bias2d, zT);
  k2_tcn<<<dim3(25, 64), dim3(256), 0, stream>>>(zT, w2t, invadd, x, out);
  k3_copyA<<<dim3((120000 + 255) / 256), dim3(256), 0, stream>>>(A, out + 30720000);
}